// Round 1
// 141.567 us; speedup vs baseline: 1.0344x; 1.0344x over previous
//
#include <hip/hip_runtime.h>
#include <math.h>

#define KDIM 8192
#define BATCH 512
#define PDIM 4096
#define CHUNK 2048      // k-entries per block in stage 1 (4 chunks per batch)

// ---------------------------------------------------------------------------
// Kernel 1: flash-style partial softmax-weighted outer-product accumulation.
// Grid: BATCH*4 blocks x 256 threads. Block (b, c) handles k in [c*2048, ...).
// Writes 12 floats per chunk: [sum_e, A00..A33 (10 upper-tri), mx]
// using the CHUNK-LOCAL max as the softmax shift (rescaled at combine time).
// ---------------------------------------------------------------------------
__global__ __launch_bounds__(256) void k_partial(
    const float* __restrict__ sep, const float* __restrict__ ohm,
    float* __restrict__ Cbuf)
{
    __shared__ float ss[CHUNK];   // 8 KB
    __shared__ float red[64];
    const int blk  = blockIdx.x;
    const int b    = blk >> 2;
    const int c    = blk & 3;
    const int tid  = threadIdx.x;
    const int lane = tid & 63, wave = tid >> 6;

    const float4* s4  = (const float4*)(sep + (size_t)b * KDIM + c * CHUNK);
    float4*       ss4 = (float4*)ss;
    float mx = -INFINITY;
    #pragma unroll
    for (int i = 0; i < CHUNK / 4 / 256; i++) {
        float4 v = s4[tid + i * 256];
        ss4[tid + i * 256] = v;
        mx = fmaxf(mx, fmaxf(fmaxf(v.x, v.y), fmaxf(v.z, v.w)));
    }
    #pragma unroll
    for (int off = 32; off > 0; off >>= 1)
        mx = fmaxf(mx, __shfl_down(mx, off, 64));
    if (lane == 0) red[wave] = mx;
    __syncthreads();
    mx = fmaxf(fmaxf(red[0], red[1]), fmaxf(red[2], red[3]));

    float acc[11];
    #pragma unroll
    for (int i = 0; i < 11; i++) acc[i] = 0.f;

    const float4* q4 = (const float4*)(ohm + ((size_t)b * KDIM + c * CHUNK) * 4);
    #pragma unroll
    for (int j = 0; j < CHUNK / 256; j++) {
        const int k = j * 256 + tid;
        float4 q = q4[k];
        float e  = __expf(ss[k] - mx);
        float ex = e * q.x, ey = e * q.y, ez = e * q.z, ew = e * q.w;
        acc[0]  += e;
        acc[1]  += ex * q.x; acc[2] += ex * q.y; acc[3] += ex * q.z; acc[4] += ex * q.w;
        acc[5]  += ey * q.y; acc[6] += ey * q.z; acc[7] += ey * q.w;
        acc[8]  += ez * q.z; acc[9] += ez * q.w;
        acc[10] += ew * q.w;
    }

    __syncthreads();
    #pragma unroll
    for (int i = 0; i < 11; i++) {
        float s = acc[i];
        #pragma unroll
        for (int off = 32; off > 0; off >>= 1)
            s += __shfl_down(s, off, 64);
        if (lane == 0) red[wave * 12 + i] = s;
    }
    __syncthreads();
    if (tid < 11)
        Cbuf[blk * 12 + tid] = red[tid] + red[12 + tid] + red[24 + tid] + red[36 + tid];
    if (tid == 11)
        Cbuf[blk * 12 + 11] = mx;
}

// ---------------------------------------------------------------------------
// Kernel 2: combine chunks + fp32 Jacobi on EXPLICIT SCALARS (no arrays ->
// no scratch possible). Symmetric storage: 10 unique A entries + 16 V entries.
// One thread per batch; emits D = R_pred - R_gt (9 floats/batch).
//
// Perf notes (R1):
//  - sweep loop is "#pragma unroll 1": fully-unrolled code (48 ROT bodies w/
//    precise div/sqrt sequences) blew past the I-cache; single wave per CU
//    cannot hide cold instruction fetch -> measured ~4400 cyc/rotation,
//    VALUBusy 0.08%. Loop body (one sweep) stays I$-resident.
//  - v_rcp_f32 / v_sqrt_f32 / v_rsq_f32 builtins (1-2 ulp) instead of precise
//    division/sqrt sequences: Jacobi rotations are self-correcting, and the
//    result is averaged over 512x4096 points.
// ---------------------------------------------------------------------------
// Pivot (p,q), other indices (r,s). APP/AQQ/APQ: pivot entries. ARP=a[r][p],
// ARQ=a[r][q], ASP=a[s][p], ASQ=a[s][q] (symmetric, sorted names).
// VPi=v[i][p], VQi=v[i][q].
#define ROT(APP, AQQ, APQ, ARP, ARQ, ASP, ASQ,                              \
            VP0, VQ0, VP1, VQ1, VP2, VQ2, VP3, VQ3)                         \
    {                                                                       \
        float apq = APQ;                                                    \
        float theta = (AQQ - APP) * 0.5f * __builtin_amdgcn_rcpf(apq);      \
        float den = fabsf(theta) +                                          \
                    __builtin_amdgcn_sqrtf(theta * theta + 1.0f);           \
        float t = copysignf(__builtin_amdgcn_rcpf(den), theta);             \
        t = (fabsf(apq) > 0.0f) ? t : 0.0f;                                 \
        float c = __builtin_amdgcn_rsqf(t * t + 1.0f);                      \
        float s = t * c;                                                    \
        float app = APP, aqq = AQQ;                                         \
        APP = c*c*app - 2.0f*s*c*apq + s*s*aqq;                             \
        AQQ = s*s*app + 2.0f*s*c*apq + c*c*aqq;                             \
        APQ = 0.0f;                                                         \
        float x;                                                            \
        x = ARP; ARP = c*x - s*ARQ; ARQ = s*x + c*ARQ;                      \
        x = ASP; ASP = c*x - s*ASQ; ASQ = s*x + c*ASQ;                      \
        x = VP0; VP0 = c*x - s*VQ0; VQ0 = s*x + c*VQ0;                      \
        x = VP1; VP1 = c*x - s*VQ1; VQ1 = s*x + c*VQ1;                      \
        x = VP2; VP2 = c*x - s*VQ2; VQ2 = s*x + c*VQ2;                      \
        x = VP3; VP3 = c*x - s*VQ3; VQ3 = s*x + c*VQ3;                      \
    }

__global__ __launch_bounds__(64, 1) void k_eig(
    const float* __restrict__ Cbuf, const float* __restrict__ gt,
    float* __restrict__ Dbuf)
{
    int b = blockIdx.x * 64 + threadIdx.x;
    if (b >= BATCH) return;
    const float* C = Cbuf + b * 48;

    // flash-combine the 4 chunks (normalization constant cancels in eigvecs)
    float mg = fmaxf(fmaxf(C[11], C[23]), fmaxf(C[35], C[47]));
    float f0 = __expf(C[11] - mg), f1 = __expf(C[23] - mg);
    float f2 = __expf(C[35] - mg), f3 = __expf(C[47] - mg);
    float inv = __builtin_amdgcn_rcpf(f0*C[0] + f1*C[12] + f2*C[24] + f3*C[36]);
    #define CMB(i) ((f0*C[1+(i)] + f1*C[13+(i)] + f2*C[25+(i)] + f3*C[37+(i)]) * inv)
    float a00 = CMB(0), a01 = CMB(1), a02 = CMB(2), a03 = CMB(3);
    float a11 = CMB(4), a12 = CMB(5), a13 = CMB(6);
    float a22 = CMB(7), a23 = CMB(8), a33 = CMB(9);
    #undef CMB

    float v00 = 1.f, v01 = 0.f, v02 = 0.f, v03 = 0.f;
    float v10 = 0.f, v11 = 1.f, v12 = 0.f, v13 = 0.f;
    float v20 = 0.f, v21 = 0.f, v22 = 1.f, v23 = 0.f;
    float v30 = 0.f, v31 = 0.f, v32 = 0.f, v33 = 1.f;

    #pragma unroll 1
    for (int sweep = 0; sweep < 8; ++sweep) {
        // (p,q)=(0,1), others 2,3
        ROT(a00, a11, a01, a02, a12, a03, a13,
            v00, v01, v10, v11, v20, v21, v30, v31)
        // (0,2), others 1,3
        ROT(a00, a22, a02, a01, a12, a03, a23,
            v00, v02, v10, v12, v20, v22, v30, v32)
        // (0,3), others 1,2
        ROT(a00, a33, a03, a01, a13, a02, a23,
            v00, v03, v10, v13, v20, v23, v30, v33)
        // (1,2), others 0,3
        ROT(a11, a22, a12, a01, a02, a13, a23,
            v01, v02, v11, v12, v21, v22, v31, v32)
        // (1,3), others 0,2
        ROT(a11, a33, a13, a01, a03, a12, a23,
            v01, v03, v11, v13, v21, v23, v31, v33)
        // (2,3), others 0,1
        ROT(a22, a33, a23, a02, a03, a12, a13,
            v02, v03, v12, v13, v22, v23, v32, v33)
    }

    // argmax eigenvalue -> eigenvector column (branch-free selects)
    float qr, qi, qj, qk, bestv;
    bestv = a00; qr = v00; qi = v10; qj = v20; qk = v30;
    if (a11 > bestv) { bestv = a11; qr = v01; qi = v11; qj = v21; qk = v31; }
    if (a22 > bestv) { bestv = a22; qr = v02; qi = v12; qj = v22; qk = v32; }
    if (a33 > bestv) { bestv = a33; qr = v03; qi = v13; qj = v23; qk = v33; }
    float ps = 2.0f / (qr*qr + qi*qi + qj*qj + qk*qk);

    float gr = gt[b*4+0], gi = gt[b*4+1], gj = gt[b*4+2], gk = gt[b*4+3];
    float gs = 2.0f / (gr*gr + gi*gi + gj*gj + gk*gk);

    // D = R_pred - R_gt, row-major (eigenvector sign irrelevant: even in q)
    float* D = Dbuf + b * 9;
    D[0] = (1.0f - ps*(qj*qj + qk*qk)) - (1.0f - gs*(gj*gj + gk*gk));
    D[1] = (ps*(qi*qj - qk*qr))        - (gs*(gi*gj - gk*gr));
    D[2] = (ps*(qi*qk + qj*qr))        - (gs*(gi*gk + gj*gr));
    D[3] = (ps*(qi*qj + qk*qr))        - (gs*(gi*gj + gk*gr));
    D[4] = (1.0f - ps*(qi*qi + qk*qk)) - (1.0f - gs*(gi*gi + gk*gk));
    D[5] = (ps*(qj*qk - qi*qr))        - (gs*(gj*gk - gi*gr));
    D[6] = (ps*(qi*qk - qj*qr))        - (gs*(gi*gk - gj*gr));
    D[7] = (ps*(qj*qk + qi*qr))        - (gs*(gj*gk + gi*gr));
    D[8] = (1.0f - ps*(qi*qi + qj*qj)) - (1.0f - gs*(gi*gi + gj*gj));
}

// ---------------------------------------------------------------------------
// Kernel 3: ||p . D|| per point, accumulate per block.
// ---------------------------------------------------------------------------
__global__ __launch_bounds__(256) void k_points(
    const float* __restrict__ point, const float* __restrict__ Dbuf,
    float* __restrict__ partial)
{
    const int blk   = blockIdx.x;
    const int b     = blk >> 2;
    const int chunk = blk & 3;
    const int tid   = threadIdx.x;
    const int lane  = tid & 63, wave = tid >> 6;
    __shared__ float red[4];

    const float* Dp = Dbuf + b * 9;
    float d[9];
    #pragma unroll
    for (int i = 0; i < 9; i++) d[i] = Dp[i];

    const float4* base = (const float4*)(point + ((size_t)b * PDIM + chunk * 1024) * 3);
    float4 v0 = base[tid * 3 + 0];
    float4 v1 = base[tid * 3 + 1];
    float4 v2 = base[tid * 3 + 2];
    float px[4] = { v0.x, v0.w, v1.z, v2.y };
    float py[4] = { v0.y, v1.x, v1.w, v2.z };
    float pz[4] = { v0.z, v1.y, v2.x, v2.w };

    float sum = 0.f;
    #pragma unroll
    for (int t = 0; t < 4; t++) {
        float x = px[t], y = py[t], z = pz[t];
        float dx = x*d[0] + y*d[3] + z*d[6];
        float dy = x*d[1] + y*d[4] + z*d[7];
        float dz = x*d[2] + y*d[5] + z*d[8];
        sum += sqrtf(dx*dx + dy*dy + dz*dz);
    }
    #pragma unroll
    for (int off = 32; off > 0; off >>= 1)
        sum += __shfl_down(sum, off, 64);
    if (lane == 0) red[wave] = sum;
    __syncthreads();
    if (tid == 0) partial[blk] = red[0] + red[1] + red[2] + red[3];
}

// ---------------------------------------------------------------------------
// Kernel 4: reduce 2048 partials in fp64, write mean.
// ---------------------------------------------------------------------------
__global__ __launch_bounds__(256) void k_final(
    const float* __restrict__ partial, float* __restrict__ out)
{
    const int tid  = threadIdx.x;
    const int lane = tid & 63, wave = tid >> 6;
    __shared__ double red[4];
    double s = 0.0;
    for (int i = tid; i < 2048; i += 256) s += (double)partial[i];
    #pragma unroll
    for (int off = 32; off > 0; off >>= 1)
        s += __shfl_down(s, off, 64);
    if (lane == 0) red[wave] = s;
    __syncthreads();
    if (tid == 0)
        out[0] = (float)((red[0] + red[1] + red[2] + red[3]) /
                         (double)((size_t)BATCH * PDIM));
}

extern "C" void kernel_launch(void* const* d_in, const int* in_sizes, int n_in,
                              void* d_out, int out_size, void* d_ws, size_t ws_size,
                              hipStream_t stream)
{
    const float* sep   = (const float*)d_in[0];   // (512, 8192)
    const float* ohm   = (const float*)d_in[1];   // (512, 8192, 4)
    const float* gt    = (const float*)d_in[2];   // (512, 4)
    const float* point = (const float*)d_in[3];   // (512, 4096, 3)
    float* out = (float*)d_out;

    float* Cbuf = (float*)d_ws;                 // 2048*12 floats
    float* Dbuf = Cbuf + BATCH * 4 * 12;        // 512*9 floats
    float* Pbuf = Dbuf + BATCH * 9;             // 2048 floats

    k_partial<<<BATCH * 4, 256, 0, stream>>>(sep, ohm, Cbuf);
    k_eig<<<8, 64, 0, stream>>>(Cbuf, gt, Dbuf);
    k_points<<<2048, 256, 0, stream>>>(point, Dbuf, Pbuf);
    k_final<<<1, 256, 0, stream>>>(Pbuf, out);
}